// Round 7
// baseline (1589.947 us; speedup 1.0000x reference)
//
#include <hip/hip_runtime.h>

// T2ICrossAttentionPool on MI355X.
// Identities: w12[c,i,w] = sum_r attn*Sraw;  |wctx|^2 = a^T G a with
//   G = exact fp32 diag (register math) + off-diag G' bf16 (MFMA quadratic form).
// R6 post-mortem: swizzled global_load_lds deposits fixed the conflict storm
//   (1.27e9 -> 2.64e8), k_main 1266 us. Still latency-bound: no pipe >25%,
//   2 blocks/CU (96-reg accumulator forbids 3 waves/SIMD -- R4 spill lesson).
// R7: slim waves. Block = 1 cap x 4 imgs, wave = 1 cap x 1 img (M=64,N=48):
//   acc 24 tiles -> 12 tiles = 48 regs, LDS 40.9 -> 35.8 KB => 3 blocks/CU
//   (12 waves/CU). Epilogue's img-loop disappears. B-staging traffic doubles
//   but L2 BW has ~8x headroom (0.5 of 4.3 TB/s per XCD).

#define NIMG 256
#define NREG 36
#define NREG_PAD 48
#define DIM 1024
#define NCAP 256
#define MAXW 60
#define WPAD 64

typedef short bf16x8 __attribute__((ext_vector_type(8)));
typedef float f32x4 __attribute__((ext_vector_type(4)));

__device__ __forceinline__ unsigned short f2bf(float f) {
  unsigned u = __float_as_uint(f);
  u += 0x7FFF + ((u >> 16) & 1);   // round-to-nearest-even
  return (unsigned short)(u >> 16);
}

__device__ __forceinline__ void gload16_lds(const void* g, void* l) {
  __builtin_amdgcn_global_load_lds(
      (const __attribute__((address_space(1))) unsigned int*)g,
      (__attribute__((address_space(3))) unsigned int*)l, 16, 0, 0);
}

// ---- prep: caps -> masked bf16 q [C][64][D] (zero rows w>=cap_len), w1[c][w]=||q row|| ----
__global__ void k_prep_caps(const float* __restrict__ caps, const int* __restrict__ cap_lens,
                            unsigned short* __restrict__ qbf, float* __restrict__ w1) {
  const int bid = blockIdx.x;          // c*64 + w
  const int c = bid >> 6;
  const int w = bid & 63;
  const int t = threadIdx.x;
  const bool valid = (w < MAXW) && (w < cap_lens[c]);
  float4 v = make_float4(0.f, 0.f, 0.f, 0.f);
  if (valid) v = *reinterpret_cast<const float4*>(caps + ((size_t)c * MAXW + w) * DIM + t * 4);
  ushort4 o;
  o.x = f2bf(v.x); o.y = f2bf(v.y); o.z = f2bf(v.z); o.w = f2bf(v.w);
  *reinterpret_cast<ushort4*>(qbf + (size_t)bid * DIM + t * 4) = o;
  float ss = v.x * v.x + v.y * v.y + v.z * v.z + v.w * v.w;
#pragma unroll
  for (int m = 1; m <= 32; m <<= 1) ss += __shfl_xor(ss, m);
  __shared__ float part[4];
  if ((t & 63) == 0) part[t >> 6] = ss;
  __syncthreads();
  if (t == 0) w1[bid] = sqrtf(part[0] + part[1] + part[2] + part[3]);
}

// ---- prep: imgs -> bf16 [I][48][D], rows 36..47 zero ----
__global__ void k_prep_imgs(const float* __restrict__ imgs, unsigned short* __restrict__ ibf) {
  const int bid = blockIdx.x;          // i*48 + r
  const int i = bid / NREG_PAD;
  const int r = bid - i * NREG_PAD;
  const int t = threadIdx.x;
  float4 v = make_float4(0.f, 0.f, 0.f, 0.f);
  if (r < NREG) v = *reinterpret_cast<const float4*>(imgs + ((size_t)i * NREG + r) * DIM + t * 4);
  ushort4 o;
  o.x = f2bf(v.x); o.y = f2bf(v.y); o.z = f2bf(v.z); o.w = f2bf(v.w);
  *reinterpret_cast<ushort4*>(ibf + (size_t)bid * DIM + t * 4) = o;
}

// ---- prep: Gram -> off-diag bf16 G'[i][48][64] (rows/cols>=36 and diag zero) + fp32 diag[i][48] ----
__device__ __forceinline__ void pairDecode(int p, int& r, int& c) {
  r = 0;
  while (p >= NREG - r) { p -= NREG - r; ++r; }
  c = r + p;
}

__global__ void k_gram(const float* __restrict__ imgs, unsigned short* __restrict__ gbf,
                       float* __restrict__ gdiag) {
  __shared__ float tile[NREG * 129];
  const int i = blockIdx.x;
  const int t = threadIdx.x;
  unsigned short* g = gbf + (size_t)i * (48 * 64);
  // zero exactly the entries the pair phase does NOT write (no race, no barrier needed)
  for (int idx = t; idx < 48 * 64; idx += 256) {
    int rr = idx >> 6, cc = idx & 63;
    if (rr >= NREG || cc >= NREG || rr == cc) g[idx] = 0;
  }
  if (t >= NREG && t < 48) gdiag[(size_t)i * 48 + t] = 0.f;

  const int NP = NREG * (NREG + 1) / 2;   // 666 pairs (incl. diag)
  int r0 = 0, q0 = 0, r1 = 0, q1 = 0, r2 = 0, q2 = 0;
  const bool v0 = (t < NP), v1 = (t + 256 < NP), v2 = (t + 512 < NP);
  if (v0) pairDecode(t, r0, q0);
  if (v1) pairDecode(t + 256, r1, q1);
  if (v2) pairDecode(t + 512, r2, q2);
  float s0 = 0.f, s1 = 0.f, s2 = 0.f;
  for (int kk = 0; kk < DIM; kk += 128) {
    __syncthreads();
    for (int idx = t; idx < NREG * 128; idx += 256) {
      int r = idx >> 7, k = idx & 127;
      tile[r * 129 + k] = imgs[((size_t)i * NREG + r) * DIM + kk + k];
    }
    __syncthreads();
    for (int k = 0; k < 128; ++k) {
      if (v0) s0 += tile[r0 * 129 + k] * tile[q0 * 129 + k];
      if (v1) s1 += tile[r1 * 129 + k] * tile[q1 * 129 + k];
      if (v2) s2 += tile[r2 * 129 + k] * tile[q2 * 129 + k];
    }
  }
  float* d = gdiag + (size_t)i * 48;
  if (v0) { if (r0 == q0) d[r0] = s0; else { unsigned short b = f2bf(s0); g[r0 * 64 + q0] = b; g[q0 * 64 + r0] = b; } }
  if (v1) { if (r1 == q1) d[r1] = s1; else { unsigned short b = f2bf(s1); g[r1 * 64 + q1] = b; g[q1 * 64 + r1] = b; } }
  if (v2) { if (r2 == q2) d[r2] = s2; else { unsigned short b = f2bf(s2); g[r2 * 64 + q2] = b; g[q2 * 64 + r2] = b; } }
}

// ---- main fused kernel ----
// Grid: (I/4, C). Block 256 = 4 waves; wave wv -> caption c (shared), image i0+wv.
// Per-wave S tile: M=64 (one caption, W padded), N=48 (1 image, padded R), K=1024.
// Staging via global_load_lds with XOR-swizzled deposits:
//   lane l fetches row m0+(l>>3), logical unit (l&7)^((l>>3)&7); the HW deposit
//   (base + lane*16) then lands at physical unit u_log ^ (row&7), so fragment
//   reads use unit = ub ^ (row&7) -> conflict-free.
#define BK 64

union MainLds {
  struct { unsigned short A[64 * 64]; unsigned short B[192 * 64]; } st;   // 32768 B
  struct {
    unsigned short attn[4][64 * 64];  // attn bf16 rows [w][64], swizzled  32768 B
    float w12[4][64];
    float w2d[4][64];
    float w2x[4][64];                 //                                     3072 B
  } ep;                               // 35840 B -> 3 blocks/CU
};

__launch_bounds__(256, 3)
__global__ void k_main(const unsigned short* __restrict__ qbf,
                       const unsigned short* __restrict__ ibf,
                       const float* __restrict__ w1,
                       const unsigned short* __restrict__ gbf,
                       const float* __restrict__ gdiag,
                       const int* __restrict__ cap_lens,
                       float* __restrict__ out) {
  __shared__ MainLds lds;
  const int tid = threadIdx.x;
  const int lane = tid & 63;
  const int l15 = lane & 15;
  const int quad = lane >> 4;
  const int wv = tid >> 6;
  const int i0 = blockIdx.x * 4;
  const int c = blockIdx.y;
  const int img = i0 + wv;             // this wave's image
  const int clen = cap_lens[c];

  f32x4 acc[4][3];
  const f32x4 zero4 = {0.f, 0.f, 0.f, 0.f};
#pragma unroll
  for (int mt = 0; mt < 4; ++mt)
#pragma unroll
    for (int nt = 0; nt < 3; ++nt) acc[mt][nt] = zero4;

  const int bRow = wv * 48;
  const int lrow = lane >> 3;                 // row-within-8 handled by this lane
  const int lu = (lane & 7) ^ (lrow & 7);     // LOGICAL 16B unit this lane fetches

  for (int kk = 0; kk < DIM; kk += BK) {
    // stage A: 64 rows x 64 halves; wave wv deposits rows [wv*8+j*32 .. +8)
#pragma unroll
    for (int j = 0; j < 2; ++j) {
      const int m0 = wv * 8 + j * 32;                      // wave-uniform, mult of 8
      const int m = m0 + lrow;
      gload16_lds(qbf + ((size_t)(c * 64 + m)) * DIM + kk + (lu << 3),
                  &lds.st.A[m0 * 64]);
    }
    // stage B: 192 rows x 64 halves
#pragma unroll
    for (int j = 0; j < 6; ++j) {
      const int n0 = wv * 8 + j * 32;
      const int n = n0 + lrow;
      gload16_lds(ibf + ((size_t)(i0 * NREG_PAD + n)) * DIM + kk + (lu << 3),
                  &lds.st.B[n0 * 64]);
    }
    __syncthreads();   // drains vmcnt (incl. the lds-loads) then barrier
#pragma unroll
    for (int ks = 0; ks < 2; ++ks) {
      const int ub = ks * 4 + quad;       // logical 16B-unit index within the row
      bf16x8 fa[4], fb[3];
#pragma unroll
      for (int mt = 0; mt < 4; ++mt) {
        const int r = mt * 16 + l15;
        fa[mt] = *reinterpret_cast<const bf16x8*>(&lds.st.A[r * 64 + ((ub ^ (r & 7)) << 3)]);
      }
#pragma unroll
      for (int nt = 0; nt < 3; ++nt) {
        const int r = bRow + nt * 16 + l15;
        fb[nt] = *reinterpret_cast<const bf16x8*>(&lds.st.B[r * 64 + ((ub ^ (r & 7)) << 3)]);
      }
#pragma unroll
      for (int mt = 0; mt < 4; ++mt)
#pragma unroll
        for (int nt = 0; nt < 3; ++nt)
          acc[mt][nt] = __builtin_amdgcn_mfma_f32_16x16x32_bf16(fa[mt], fb[nt], acc[mt][nt], 0, 0, 0);
    }
    __syncthreads();
  }

  // ---- epilogue (each wave owns one image; all LDS below is wave-private) ----
  // zero attn buffers once (K-pad cols 48..63 must stay 0 for the Y-MFMA)
  {
    const uint4 z4 = make_uint4(0, 0, 0, 0);
    uint4* ab = reinterpret_cast<uint4*>(&lds.ep.attn[0][0]);
    for (int idx = tid; idx < 2048; idx += 256) ab[idx] = z4;
  }
  __syncthreads();

  const int lo = l15 & 7, hi = l15 >> 3;

  const float* dg = gdiag + (size_t)img * 48;
  const float d0 = dg[l15];
  const float d1 = dg[16 + l15];
  const float d2 = dg[32 + l15];
  // per-region l2 norm over w (C-layout: rows live across quads -> xor 16,32)
  float scale[3];
#pragma unroll
  for (int nt = 0; nt < 3; ++nt) {
    float p = 0.f;
#pragma unroll
    for (int mt = 0; mt < 4; ++mt)
#pragma unroll
      for (int rg = 0; rg < 4; ++rg) {
        float s = acc[mt][nt][rg];
        float l = s < 0.f ? 0.1f * s : s;
        p += l * l;
      }
    p += __shfl_xor(p, 16);
    p += __shfl_xor(p, 32);
    scale[nt] = 9.0f / (sqrtf(p) + 1e-8f);   // SMOOTH folded in
  }
  const bool vr2 = (l15 < 4);   // r = 32+l15 valid only if < 36
  // softmax over r (cols across the 16 lanes of a quad -> xor 1..8), w12, diag, attn->LDS
#pragma unroll
  for (int mt = 0; mt < 4; ++mt) {
#pragma unroll
    for (int rg = 0; rg < 4; ++rg) {
      const float s0 = acc[mt][0][rg];
      const float s1 = acc[mt][1][rg];
      const float s2 = acc[mt][2][rg];
      const float t0 = (s0 < 0.f ? 0.1f * s0 : s0) * scale[0];
      const float t1 = (s1 < 0.f ? 0.1f * s1 : s1) * scale[1];
      const float t2 = (s2 < 0.f ? 0.1f * s2 : s2) * scale[2];
      float mx = fmaxf(t0, t1);
      if (vr2) mx = fmaxf(mx, t2);
      mx = fmaxf(mx, __shfl_xor(mx, 1));
      mx = fmaxf(mx, __shfl_xor(mx, 2));
      mx = fmaxf(mx, __shfl_xor(mx, 4));
      mx = fmaxf(mx, __shfl_xor(mx, 8));
      const float e0 = __expf(t0 - mx);
      const float e1 = __expf(t1 - mx);
      const float e2 = vr2 ? __expf(t2 - mx) : 0.f;
      float sm = e0 + e1 + e2;
      sm += __shfl_xor(sm, 1);
      sm += __shfl_xor(sm, 2);
      sm += __shfl_xor(sm, 4);
      sm += __shfl_xor(sm, 8);
      const float inv = 1.0f / sm;
      const float a0 = e0 * inv, a1 = e1 * inv, a2 = e2 * inv;   // a2==0 when invalid
      float wp = a0 * s0 + a1 * s1 + a2 * s2;                    // w12 uses RAW s
      float dd = a0 * a0 * d0 + a1 * a1 * d1 + a2 * a2 * d2;     // exact diag term
      wp += __shfl_xor(wp, 1); wp += __shfl_xor(wp, 2);
      wp += __shfl_xor(wp, 4); wp += __shfl_xor(wp, 8);
      dd += __shfl_xor(dd, 1); dd += __shfl_xor(dd, 2);
      dd += __shfl_xor(dd, 4); dd += __shfl_xor(dd, 8);
      const int w = mt * 16 + quad * 4 + rg;
      const int w7 = w & 7;
      unsigned short* arow = &lds.ep.attn[wv][w * 64];
      arow[(((0 + hi) ^ w7) << 3) + lo] = f2bf(a0);
      arow[(((2 + hi) ^ w7) << 3) + lo] = f2bf(a1);
      arow[(((4 + hi) ^ w7) << 3) + lo] = f2bf(a2);
      if (l15 == 0) { lds.ep.w12[wv][w] = wp; lds.ep.w2d[wv][w] = dd; }
    }
  }
  // Y = Attn x G' via MFMA (wave-private; in-wave lgkmcnt ordering suffices).
  // G' B-fragments straight from global (hot in L2; 1.5 MB table).
  bf16x8 gfrag[3][2];
#pragma unroll
  for (int nt = 0; nt < 3; ++nt)
#pragma unroll
    for (int ks = 0; ks < 2; ++ks)
      gfrag[nt][ks] = *reinterpret_cast<const bf16x8*>(
          gbf + ((size_t)img * 48 + nt * 16 + l15) * 64 + ((ks * 4 + quad) << 3));
#pragma unroll
  for (int mt = 0; mt < 4; ++mt) {
    bf16x8 af[2];
#pragma unroll
    for (int ks = 0; ks < 2; ++ks)
      af[ks] = *reinterpret_cast<const bf16x8*>(
          &lds.ep.attn[wv][(mt * 16 + l15) * 64 + (((ks * 4 + quad) ^ (l15 & 7)) << 3)]);
    f32x4 Y[3] = {zero4, zero4, zero4};
#pragma unroll
    for (int nt = 0; nt < 3; ++nt)
#pragma unroll
      for (int ks = 0; ks < 2; ++ks)
        Y[nt] = __builtin_amdgcn_mfma_f32_16x16x32_bf16(af[ks], gfrag[nt][ks], Y[nt], 0, 0, 0);
    // cross term: w2x[w] = sum_{r'} a[w][r'] * Y[w][r']  (Y C-layout == a C-layout)
#pragma unroll
    for (int rg = 0; rg < 4; ++rg) {
      const int w = mt * 16 + quad * 4 + rg;
      const int w7 = w & 7;
      float p = 0.f;
#pragma unroll
      for (int nt = 0; nt < 3; ++nt) {
        const unsigned short b = lds.ep.attn[wv][w * 64 + (((nt * 2 + hi) ^ w7) << 3) + lo];
        p += __uint_as_float((unsigned)b << 16) * Y[nt][rg];
      }
      p += __shfl_xor(p, 1); p += __shfl_xor(p, 2);
      p += __shfl_xor(p, 4); p += __shfl_xor(p, 8);
      if (l15 == 0) lds.ep.w2x[wv][w] = p;
    }
  }
  // final: lane = word
  float simv = 0.f;
  if (lane < clen) {
    const float w2sq = fmaxf(lds.ep.w2x[wv][lane] + lds.ep.w2d[wv][lane], 0.f);
    const float w2v = sqrtf(w2sq);
    const float w12v = lds.ep.w12[wv][lane];
    const float w1v = w1[(size_t)c * WPAD + lane];
    simv = w12v / fmaxf(w1v * w2v, 1e-8f);
  }
  simv += __shfl_xor(simv, 1);
  simv += __shfl_xor(simv, 2);
  simv += __shfl_xor(simv, 4);
  simv += __shfl_xor(simv, 8);
  simv += __shfl_xor(simv, 16);
  simv += __shfl_xor(simv, 32);
  if (lane == 0) out[(size_t)img * NCAP + c] = simv / (float)clen;
}

extern "C" void kernel_launch(void* const* d_in, const int* in_sizes, int n_in,
                              void* d_out, int out_size, void* d_ws, size_t ws_size,
                              hipStream_t stream) {
  const float* imgs = (const float*)d_in[0];
  const float* caps = (const float*)d_in[1];
  const int* cap_lens = (const int*)d_in[3];   // img_lens (d_in[2]) unused by reference
  float* out = (float*)d_out;

  char* ws = (char*)d_ws;
  const size_t QBF_B = (size_t)NCAP * WPAD * DIM * 2;        // 33,554,432
  const size_t IBF_B = (size_t)NIMG * NREG_PAD * DIM * 2;    // 25,165,824
  const size_t W1_B = (size_t)NCAP * WPAD * 4;               // 65,536
  const size_t GBF_B = (size_t)NIMG * 48 * 64 * 2;           // 1,572,864
  unsigned short* qbf = (unsigned short*)ws;
  unsigned short* ibf = (unsigned short*)(ws + QBF_B);
  float* w1 = (float*)(ws + QBF_B + IBF_B);
  unsigned short* gbf = (unsigned short*)(ws + QBF_B + IBF_B + W1_B);
  float* gdiag = (float*)(ws + QBF_B + IBF_B + W1_B + GBF_B);

  k_prep_caps<<<NCAP * WPAD, 256, 0, stream>>>(caps, cap_lens, qbf, w1);
  k_prep_imgs<<<NIMG * NREG_PAD, 256, 0, stream>>>(imgs, ibf);
  k_gram<<<NIMG, 256, 0, stream>>>(imgs, gbf, gdiag);
  k_main<<<dim3(NIMG / 4, NCAP), 256, 0, stream>>>(qbf, ibf, w1, gbf, gdiag, cap_lens, out);
}

// Round 8
// 851.291 us; speedup vs baseline: 1.8677x; 1.8677x over previous
//
#include <hip/hip_runtime.h>

// T2ICrossAttentionPool on MI355X.
// Identities: w12[c,i,w] = sum_r attn*Sraw;  |wctx|^2 = a^T G a with
//   G = exact fp32 diag (register math) + off-diag G' bf16 (MFMA quadratic form).
// R7 post-mortem: kernel was LDS-PIPE-bound (~82 MB reads + 41 MB deposits per
//   CU; occupancy bump didn't help, extra B traffic hurt). Fragment bytes/MFMA
//   are invariant to tiling -> remove LDS from the K-loop entirely.
// R8: prep kernels emit A/B in MFMA FRAGMENT ORDER; the K-loop loads each
//   fragment as one coalesced global_load_dwordx4 (1 KB/wave) from L2.
//   No deposits, no ds_read, no __syncthreads -> no barrier drain. Register
//   double-buffered 2-stage pipeline (K=32/stage). Dynamic-M: skip mt tiles
//   >= ceil(clen/16) (wave-uniform), avg 37.5% less MFMA/A-traffic/epilogue.
//   Blocks = 2 waves (2 caps x same 2 images) so partner B-frags hit L1.

#define NIMG 256
#define NREG 36
#define DIM 1024
#define NCAP 256
#define MAXW 60
#define WPAD 64

typedef short bf16x8 __attribute__((ext_vector_type(8)));
typedef float f32x4 __attribute__((ext_vector_type(4)));

__device__ __forceinline__ unsigned short f2bf(float f) {
  unsigned u = __float_as_uint(f);
  u += 0x7FFF + ((u >> 16) & 1);   // round-to-nearest-even
  return (unsigned short)(u >> 16);
}

// ---- prep: w1[c][w] = ||masked q row|| ----
__global__ void k_prep_w1(const float* __restrict__ caps, const int* __restrict__ cap_lens,
                          float* __restrict__ w1) {
  const int bid = blockIdx.x;          // c*64 + w
  const int c = bid >> 6;
  const int w = bid & 63;
  const int t = threadIdx.x;
  const bool valid = (w < MAXW) && (w < cap_lens[c]);
  float4 v = make_float4(0.f, 0.f, 0.f, 0.f);
  if (valid) v = *reinterpret_cast<const float4*>(caps + ((size_t)c * MAXW + w) * DIM + t * 4);
  float ss = v.x * v.x + v.y * v.y + v.z * v.z + v.w * v.w;
#pragma unroll
  for (int m = 1; m <= 32; m <<= 1) ss += __shfl_xor(ss, m);
  __shared__ float part[4];
  if ((t & 63) == 0) part[t >> 6] = ss;
  __syncthreads();
  if (t == 0) w1[bid] = sqrtf(part[0] + part[1] + part[2] + part[3]);
}

// ---- prep: caps -> A fragments, masked (rows w>=clen zero) ----
// Layout: qbfF[(((c*32 + k32)*4 + mt)*64 + lane)*8 + j]
//   = q[c][m = mt*16 + (lane&15)][k = k32*32 + (lane>>4)*8 + j]
__global__ void k_prep_caps_frag(const float* __restrict__ caps, const int* __restrict__ cap_lens,
                                 unsigned short* __restrict__ qbfF) {
  const int k32 = blockIdx.x;
  const int c = blockIdx.y;
  const int t = threadIdx.x;
  const int mt = t >> 6;
  const int lane = t & 63;
  const int m = mt * 16 + (lane & 15);
  const int k0 = k32 * 32 + (lane >> 4) * 8;
  const int clen = cap_lens[c];
  float4 v0 = make_float4(0.f, 0.f, 0.f, 0.f), v1 = v0;
  if (m < clen && m < MAXW) {
    const float* src = caps + ((size_t)c * MAXW + m) * DIM + k0;
    v0 = *reinterpret_cast<const float4*>(src);
    v1 = *reinterpret_cast<const float4*>(src + 4);
  }
  ushort4 o0, o1;
  o0.x = f2bf(v0.x); o0.y = f2bf(v0.y); o0.z = f2bf(v0.z); o0.w = f2bf(v0.w);
  o1.x = f2bf(v1.x); o1.y = f2bf(v1.y); o1.z = f2bf(v1.z); o1.w = f2bf(v1.w);
  unsigned short* dst = qbfF + ((size_t)(((c * 32 + k32) * 4 + mt) * 64 + lane)) * 8;
  *reinterpret_cast<ushort4*>(dst) = o0;
  *reinterpret_cast<ushort4*>(dst + 4) = o1;
}

// ---- prep: imgs -> B fragments (rows r>=36 zero) ----
// Layout: ibfF[(((i*32 + k32)*3 + nt)*64 + lane)*8 + j]
//   = imgs[i][r = nt*16 + (lane&15)][k = k32*32 + (lane>>4)*8 + j]
__global__ void k_prep_imgs_frag(const float* __restrict__ imgs,
                                 unsigned short* __restrict__ ibfF) {
  const int k32 = blockIdx.x;
  const int i = blockIdx.y;
  const int t = threadIdx.x;          // 0..191
  const int nt = t >> 6;
  const int lane = t & 63;
  const int r = nt * 16 + (lane & 15);
  const int k0 = k32 * 32 + (lane >> 4) * 8;
  float4 v0 = make_float4(0.f, 0.f, 0.f, 0.f), v1 = v0;
  if (r < NREG) {
    const float* src = imgs + ((size_t)i * NREG + r) * DIM + k0;
    v0 = *reinterpret_cast<const float4*>(src);
    v1 = *reinterpret_cast<const float4*>(src + 4);
  }
  ushort4 o0, o1;
  o0.x = f2bf(v0.x); o0.y = f2bf(v0.y); o0.z = f2bf(v0.z); o0.w = f2bf(v0.w);
  o1.x = f2bf(v1.x); o1.y = f2bf(v1.y); o1.z = f2bf(v1.z); o1.w = f2bf(v1.w);
  unsigned short* dst = ibfF + ((size_t)(((i * 32 + k32) * 3 + nt) * 64 + lane)) * 8;
  *reinterpret_cast<ushort4*>(dst) = o0;
  *reinterpret_cast<ushort4*>(dst + 4) = o1;
}

// ---- prep: Gram -> off-diag bf16 G'[i][48][64] (rows/cols>=36 and diag zero) + fp32 diag[i][48] ----
__device__ __forceinline__ void pairDecode(int p, int& r, int& c) {
  r = 0;
  while (p >= NREG - r) { p -= NREG - r; ++r; }
  c = r + p;
}

__global__ void k_gram(const float* __restrict__ imgs, unsigned short* __restrict__ gbf,
                       float* __restrict__ gdiag) {
  __shared__ float tile[NREG * 129];
  const int i = blockIdx.x;
  const int t = threadIdx.x;
  unsigned short* g = gbf + (size_t)i * (48 * 64);
  for (int idx = t; idx < 48 * 64; idx += 256) {
    int rr = idx >> 6, cc = idx & 63;
    if (rr >= NREG || cc >= NREG || rr == cc) g[idx] = 0;
  }
  if (t >= NREG && t < 48) gdiag[(size_t)i * 48 + t] = 0.f;

  const int NP = NREG * (NREG + 1) / 2;   // 666 pairs (incl. diag)
  int r0 = 0, q0 = 0, r1 = 0, q1 = 0, r2 = 0, q2 = 0;
  const bool v0 = (t < NP), v1 = (t + 256 < NP), v2 = (t + 512 < NP);
  if (v0) pairDecode(t, r0, q0);
  if (v1) pairDecode(t + 256, r1, q1);
  if (v2) pairDecode(t + 512, r2, q2);
  float s0 = 0.f, s1 = 0.f, s2 = 0.f;
  for (int kk = 0; kk < DIM; kk += 128) {
    __syncthreads();
    for (int idx = t; idx < NREG * 128; idx += 256) {
      int r = idx >> 7, k = idx & 127;
      tile[r * 129 + k] = imgs[((size_t)i * NREG + r) * DIM + kk + k];
    }
    __syncthreads();
    for (int k = 0; k < 128; ++k) {
      if (v0) s0 += tile[r0 * 129 + k] * tile[q0 * 129 + k];
      if (v1) s1 += tile[r1 * 129 + k] * tile[q1 * 129 + k];
      if (v2) s2 += tile[r2 * 129 + k] * tile[q2 * 129 + k];
    }
  }
  float* d = gdiag + (size_t)i * 48;
  if (v0) { if (r0 == q0) d[r0] = s0; else { unsigned short b = f2bf(s0); g[r0 * 64 + q0] = b; g[q0 * 64 + r0] = b; } }
  if (v1) { if (r1 == q1) d[r1] = s1; else { unsigned short b = f2bf(s1); g[r1 * 64 + q1] = b; g[q1 * 64 + r1] = b; } }
  if (v2) { if (r2 == q2) d[r2] = s2; else { unsigned short b = f2bf(s2); g[r2 * 64 + q2] = b; g[q2 * 64 + r2] = b; } }
}

// ---- main fused kernel ----
// Grid (I/2, C/2), block 128 = 2 waves. Wave wv: caption c = 2*blockIdx.y+wv,
// images i0, i0+1 (shared across the 2 waves -> partner B-frags hit L1).
// Per-wave S tile: M=64 (W padded; mt tiles >= mlim skipped), N=96, K=1024.
// K-loop: no LDS, no barriers; register-double-buffered fragment stream.
__launch_bounds__(128, 2)
__global__ void k_main(const unsigned short* __restrict__ qbfF,
                       const unsigned short* __restrict__ ibfF,
                       const float* __restrict__ w1,
                       const unsigned short* __restrict__ gbf,
                       const float* __restrict__ gdiag,
                       const int* __restrict__ cap_lens,
                       float* __restrict__ out) {
  __shared__ struct {
    unsigned short attn[2][64 * 64];  // bf16 rows [w][64], swizzled; wave-private
    float w12[2][64];
    float w2d[2][64];
    float w2x[2][64];
  } lds;                               // 17920 B
  const int tid = threadIdx.x;
  const int lane = tid & 63;
  const int wv = tid >> 6;
  const int l15 = lane & 15;
  const int quad = lane >> 4;
  const int i0 = blockIdx.x * 2;
  const int c = blockIdx.y * 2 + wv;
  const int clen = cap_lens[c];
  const int mlim = (clen + 15) >> 4;   // 1..4 valid A-tiles

  f32x4 acc[4][6];
  const f32x4 zero4 = {0.f, 0.f, 0.f, 0.f};
#pragma unroll
  for (int mt = 0; mt < 4; ++mt)
#pragma unroll
    for (int nt = 0; nt < 6; ++nt) acc[mt][nt] = zero4;

  const unsigned short* aBase = qbfF + ((size_t)c * 32 * 4) * 512 + lane * 8;
  const unsigned short* b0Base = ibfF + ((size_t)i0 * 32 * 3) * 512 + lane * 8;
  const unsigned short* b1Base = ibfF + ((size_t)(i0 + 1) * 32 * 3) * 512 + lane * 8;

  bf16x8 fa[2][4], fb[2][6];
  auto loadStage = [&](int k32, int buf) __attribute__((always_inline)) {
#pragma unroll
    for (int mt = 0; mt < 4; ++mt)
      if (mt < mlim)
        fa[buf][mt] = *reinterpret_cast<const bf16x8*>(aBase + ((size_t)k32 * 4 + mt) * 512);
#pragma unroll
    for (int nt = 0; nt < 3; ++nt) {
      fb[buf][nt]     = *reinterpret_cast<const bf16x8*>(b0Base + ((size_t)k32 * 3 + nt) * 512);
      fb[buf][3 + nt] = *reinterpret_cast<const bf16x8*>(b1Base + ((size_t)k32 * 3 + nt) * 512);
    }
  };
  auto mfmaStage = [&](int buf) __attribute__((always_inline)) {
#pragma unroll
    for (int mt = 0; mt < 4; ++mt)
      if (mt < mlim)
#pragma unroll
        for (int nt = 0; nt < 6; ++nt)
          acc[mt][nt] = __builtin_amdgcn_mfma_f32_16x16x32_bf16(fa[buf][mt], fb[buf][nt], acc[mt][nt], 0, 0, 0);
  };

  loadStage(0, 0);
  for (int k32 = 0; k32 < 32; k32 += 2) {
    loadStage(k32 + 1, 1);
    mfmaStage(0);
    if (k32 + 2 < 32) loadStage(k32 + 2, 0);
    mfmaStage(1);
  }

  // ---- epilogue (all LDS below is wave-private; no cross-wave barriers) ----
  {
    uint4* ab = reinterpret_cast<uint4*>(&lds.attn[wv][0]);
    const uint4 z4 = make_uint4(0, 0, 0, 0);
    for (int j = lane; j < 512; j += 64) ab[j] = z4;   // zero incl. K-pad cols 48..63
  }

  const int lo = l15 & 7, hi = l15 >> 3;

#pragma unroll
  for (int img = 0; img < 2; ++img) {
    const int gimg = i0 + img;
    const float* dg = gdiag + (size_t)gimg * 48;
    const float d0 = dg[l15];
    const float d1 = dg[16 + l15];
    const float d2 = dg[32 + l15];
    // per-region l2 norm over w (C-layout: rows live across quads -> xor 16,32)
    float scale[3];
#pragma unroll
    for (int nt3 = 0; nt3 < 3; ++nt3) {
      const int nt = img * 3 + nt3;
      float p = 0.f;
#pragma unroll
      for (int mt = 0; mt < 4; ++mt)
        if (mt < mlim)
#pragma unroll
          for (int rg = 0; rg < 4; ++rg) {
            float s = acc[mt][nt][rg];
            float l = s < 0.f ? 0.1f * s : s;
            p += l * l;
          }
      p += __shfl_xor(p, 16);
      p += __shfl_xor(p, 32);
      scale[nt3] = 9.0f / (sqrtf(p) + 1e-8f);   // SMOOTH folded in
    }
    const bool vr2 = (l15 < 4);   // r = 32+l15 valid only if < 36
    // softmax over r (cols across the 16 lanes of a quad -> xor 1..8), w12, diag, attn->LDS
#pragma unroll
    for (int mt = 0; mt < 4; ++mt) {
      if (mt >= mlim) continue;
#pragma unroll
      for (int rg = 0; rg < 4; ++rg) {
        const float s0 = acc[mt][img * 3 + 0][rg];
        const float s1 = acc[mt][img * 3 + 1][rg];
        const float s2 = acc[mt][img * 3 + 2][rg];
        const float t0 = (s0 < 0.f ? 0.1f * s0 : s0) * scale[0];
        const float t1 = (s1 < 0.f ? 0.1f * s1 : s1) * scale[1];
        const float t2 = (s2 < 0.f ? 0.1f * s2 : s2) * scale[2];
        float mx = fmaxf(t0, t1);
        if (vr2) mx = fmaxf(mx, t2);
        mx = fmaxf(mx, __shfl_xor(mx, 1));
        mx = fmaxf(mx, __shfl_xor(mx, 2));
        mx = fmaxf(mx, __shfl_xor(mx, 4));
        mx = fmaxf(mx, __shfl_xor(mx, 8));
        const float e0 = __expf(t0 - mx);
        const float e1 = __expf(t1 - mx);
        const float e2 = vr2 ? __expf(t2 - mx) : 0.f;
        float sm = e0 + e1 + e2;
        sm += __shfl_xor(sm, 1);
        sm += __shfl_xor(sm, 2);
        sm += __shfl_xor(sm, 4);
        sm += __shfl_xor(sm, 8);
        const float inv = 1.0f / sm;
        const float a0 = e0 * inv, a1 = e1 * inv, a2 = e2 * inv;   // a2==0 when invalid
        float wp = a0 * s0 + a1 * s1 + a2 * s2;                    // w12 uses RAW s
        float dd = a0 * a0 * d0 + a1 * a1 * d1 + a2 * a2 * d2;     // exact diag term
        wp += __shfl_xor(wp, 1); wp += __shfl_xor(wp, 2);
        wp += __shfl_xor(wp, 4); wp += __shfl_xor(wp, 8);
        dd += __shfl_xor(dd, 1); dd += __shfl_xor(dd, 2);
        dd += __shfl_xor(dd, 4); dd += __shfl_xor(dd, 8);
        const int w = mt * 16 + quad * 4 + rg;
        const int w7 = w & 7;
        unsigned short* arow = &lds.attn[wv][w * 64];
        arow[(((0 + hi) ^ w7) << 3) + lo] = f2bf(a0);
        arow[(((2 + hi) ^ w7) << 3) + lo] = f2bf(a1);
        arow[(((4 + hi) ^ w7) << 3) + lo] = f2bf(a2);
        if (l15 == 0) { lds.w12[wv][w] = wp; lds.w2d[wv][w] = dd; }
      }
    }
    // Y = Attn x G' via MFMA (wave-private; in-wave lgkmcnt ordering suffices).
    // G' B-fragments straight from global (hot in L2; 1.5 MB table).
    bf16x8 gfrag[3][2];
#pragma unroll
    for (int nt = 0; nt < 3; ++nt)
#pragma unroll
      for (int ks = 0; ks < 2; ++ks)
        gfrag[nt][ks] = *reinterpret_cast<const bf16x8*>(
            gbf + ((size_t)gimg * 48 + nt * 16 + l15) * 64 + ((ks * 4 + quad) << 3));
#pragma unroll
    for (int mt = 0; mt < 4; ++mt) {
      if (mt >= mlim) continue;
      bf16x8 af[2];
#pragma unroll
      for (int ks = 0; ks < 2; ++ks)
        af[ks] = *reinterpret_cast<const bf16x8*>(
            &lds.attn[wv][(mt * 16 + l15) * 64 + (((ks * 4 + quad) ^ (l15 & 7)) << 3)]);
      f32x4 Y[3] = {zero4, zero4, zero4};
#pragma unroll
      for (int nt = 0; nt < 3; ++nt)
#pragma unroll
        for (int ks = 0; ks < 2; ++ks)
          Y[nt] = __builtin_amdgcn_mfma_f32_16x16x32_bf16(af[ks], gfrag[nt][ks], Y[nt], 0, 0, 0);
      // cross term: w2x[w] = sum_{r'} a[w][r'] * Y[w][r']  (Y C-layout == a C-layout)
#pragma unroll
      for (int rg = 0; rg < 4; ++rg) {
        const int w = mt * 16 + quad * 4 + rg;
        const int w7 = w & 7;
        float p = 0.f;
#pragma unroll
        for (int nt = 0; nt < 3; ++nt) {
          const unsigned short b = lds.attn[wv][w * 64 + (((nt * 2 + hi) ^ w7) << 3) + lo];
          p += __uint_as_float((unsigned)b << 16) * Y[nt][rg];
        }
        p += __shfl_xor(p, 1); p += __shfl_xor(p, 2);
        p += __shfl_xor(p, 4); p += __shfl_xor(p, 8);
        if (l15 == 0) lds.w2x[wv][w] = p;
      }
    }
    // final: lane = word
    float simv = 0.f;
    if (lane < clen) {
      const float w2sq = fmaxf(lds.w2x[wv][lane] + lds.w2d[wv][lane], 0.f);
      const float w2v = sqrtf(w2sq);
      const float w12v = lds.w12[wv][lane];
      const float w1v = w1[(size_t)c * WPAD + lane];
      simv = w12v / fmaxf(w1v * w2v, 1e-8f);
    }
    simv += __shfl_xor(simv, 1);
    simv += __shfl_xor(simv, 2);
    simv += __shfl_xor(simv, 4);
    simv += __shfl_xor(simv, 8);
    simv += __shfl_xor(simv, 16);
    simv += __shfl_xor(simv, 32);
    if (lane == 0) out[(size_t)gimg * NCAP + c] = simv / (float)clen;
  }
}

extern "C" void kernel_launch(void* const* d_in, const int* in_sizes, int n_in,
                              void* d_out, int out_size, void* d_ws, size_t ws_size,
                              hipStream_t stream) {
  const float* imgs = (const float*)d_in[0];
  const float* caps = (const float*)d_in[1];
  const int* cap_lens = (const int*)d_in[3];   // img_lens (d_in[2]) unused by reference
  float* out = (float*)d_out;

  char* ws = (char*)d_ws;
  const size_t QBF_B = (size_t)NCAP * 32 * 4 * 512 * 2;      // 33,554,432
  const size_t IBF_B = (size_t)NIMG * 32 * 3 * 512 * 2;      // 25,165,824
  const size_t W1_B = (size_t)NCAP * WPAD * 4;               // 65,536
  const size_t GBF_B = (size_t)NIMG * 48 * 64 * 2;           // 1,572,864
  unsigned short* qbfF = (unsigned short*)ws;
  unsigned short* ibfF = (unsigned short*)(ws + QBF_B);
  float* w1 = (float*)(ws + QBF_B + IBF_B);
  unsigned short* gbf = (unsigned short*)(ws + QBF_B + IBF_B + W1_B);
  float* gdiag = (float*)(ws + QBF_B + IBF_B + W1_B + GBF_B);

  k_prep_w1<<<NCAP * WPAD, 256, 0, stream>>>(caps, cap_lens, w1);
  k_prep_caps_frag<<<dim3(32, NCAP), 256, 0, stream>>>(caps, cap_lens, qbfF);
  k_prep_imgs_frag<<<dim3(32, NIMG), 192, 0, stream>>>(imgs, ibfF);
  k_gram<<<NIMG, 256, 0, stream>>>(imgs, gbf, gdiag);
  k_main<<<dim3(NIMG / 2, NCAP / 2), 128, 0, stream>>>(qbfF, ibfF, w1, gbf, gdiag, cap_lens, out);
}